// Round 13
// baseline (155.001 us; speedup 1.0000x reference)
//
#include <hip/hip_runtime.h>

// NRI MLP decoder, round 19: ZERO-BARRIER wave-independent blocks.
// r18 resolved r17: row-split node math is CORRECT (absmax 0.03125);
// r17's failure was compiler LDS reordering (fences fix it). r18's
// +16us regression was self-inflicted: node weights (4x sets) loaded
// AFTER the seam barrier and pinned there by sched_barrier fences ->
// serialized L2 chain. Ledger fit across r8-r18: residency pinned at
// ~8 waves/CU regardless of VGPR/LDS/block-shape; wall ~ (waves/2048)
// x per-wave chain C; computed C ~8-10k cyc but measured ~30k -- the
// 3-4x gap is attributed to cross-wave convoy skew at the 4 barriers,
// never isolated. This round isolates it: each wave is self-contained,
// block has NO __syncthreads:
//  - V frags built in REGISTERS from global (w1s rows x per-lane x row;
//    element-identical arithmetic to the staged version, cf. r12)
//  - P/rt/X in a wave-private 1664B LDS slice
//  - node phase = r18's verified wave-private path
//  - ALL weights (edge+node) register-loaded BEFORE the edge phase
//  - r18's proven lds_fence at every LDS write->read seam
// VGPR ~180 -> 2 waves/SIMD = 8/CU = observed cap -> residency
// unchanged; experiment cleanly isolates convoy removal.
// B=8, N=64, T=50 (49 used), D=4, H=64, K=2 (only relation i=1), E=4032.
// Grid = B*49*4 = 1568 blocks, 256 threads (4 independent waves);
// wave = 4 receivers. mfma_f32_16x16x32_f16; fp32 accumulate.

#define NB 8
#define NN 64
#define NT 50
#define NTO 49
#define ND 4
#define NE 4032

typedef _Float16 f16x8 __attribute__((ext_vector_type(8)));
typedef _Float16 f16x4 __attribute__((ext_vector_type(4)));
typedef _Float16 f16x2 __attribute__((ext_vector_type(2)));
typedef float f32x4 __attribute__((ext_vector_type(4)));

union Frag8 { unsigned u[4]; f16x8 f; f16x2 h[4]; };

__device__ __forceinline__ unsigned pk16(float lo, float hi) {
  return __builtin_bit_cast(unsigned, __builtin_amdgcn_cvt_pkrtz(lo, hi));
}

__device__ __forceinline__ void lds_fence() {
  // Same-wave LDS RAW fence (r18-verified): forbid compiler reordering
  // and drain DS ops. Weights are register-resident before the first
  // fence, so the pinning cannot serialize them (r18's mistake).
  __builtin_amdgcn_sched_barrier(0);
  asm volatile("s_waitcnt lgkmcnt(0)" ::: "memory");
  __builtin_amdgcn_sched_barrier(0);
}

#define MFMA16(A, B, C) __builtin_amdgcn_mfma_f32_16x16x32_f16((A), (B), (C), 0, 0, 0)

__global__ __launch_bounds__(256) void nri_fused_kernel(
    const float* __restrict__ inputs,   // (B,N,T,D)
    const float* __restrict__ rel_type, // (B,1,E,2)
    const float* __restrict__ fc1_w,    // (2,64,8)
    const float* __restrict__ fc1_b,    // (2,64)
    const float* __restrict__ fc2_w,    // (2,64,64)
    const float* __restrict__ fc2_b,    // (2,64)
    const float* __restrict__ out1_w,   // (64,68)
    const float* __restrict__ out1_b,   // (64)
    const float* __restrict__ out2_w,   // (64,64)
    const float* __restrict__ out2_b,   // (64)
    const float* __restrict__ out3_w,   // (4,64)
    const float* __restrict__ out3_b,   // (4)
    float* __restrict__ out)            // (B,N,49,4)
{
  // Wave-private LDS slices, 1664 B each (16B-aligned), 4 waves = 6656 B:
  //   [   0,  512) RlW f16[4*64]  rt[np][s]
  //   [ 512, 1024) PhW f16[4*64]  U[np][k]+b1[k]
  //   [1024, 1600) Reg f16[4*72]  agg -> h1 -> h2
  //   [1600, 1664) XW  float4[4]  x rows of this wave's receivers
  __shared__ __align__(16) char smem[6656];

  const int bid    = blockIdx.x;
  const int tile   = bid & 3;
  const int t      = (bid >> 2) % NTO;
  const int b      = bid / (4 * NTO);
  const int n_base = tile * 16;
  const int tid  = threadIdx.x;
  const int lane = tid & 63;
  const int w    = tid >> 6;
  const int q    = lane >> 4;
  const int r    = lane & 15;

  char* const ws = smem + w * 1664;
  _Float16* const RlW = (_Float16*)ws;
  _Float16* const PhW = (_Float16*)(ws + 512);
  _Float16* const Reg = (_Float16*)(ws + 1024);
  float4*   const XW  = (float4*)(ws + 1600);

  // ---------- wave-local staging: P rows, rt, X (LDS writes) ----------
  {
    const int k = lane;
    const float4 w1r = *(const float4*)(fc1_w + 512 + k * 8);
    const float  b1k = fc1_b[64 + k];
#pragma unroll
    for (int ii = 0; ii < 4; ++ii) {             // this wave's 4 receivers
      const int n = n_base + w * 4 + ii;
      const float4 x = *(const float4*)(inputs + ((b * NN + n) * NT + t) * ND);
      PhW[ii * 64 + k] = (_Float16)(b1k + w1r.x*x.x + w1r.y*x.y + w1r.z*x.z + w1r.w*x.w);
    }
  }
#pragma unroll
  for (int j = 0; j < 4; ++j) {                  // rt: 256 entries / 64 lanes
    const int e = lane * 4 + j;
    const int ii = e >> 6, s = e & 63;
    const int n = n_base + w * 4 + ii;
    const float v = (s == n) ? 0.f
                  : rel_type[(b * NE + n * 63 + (s < n ? s : s - 1)) * 2 + 1];
    RlW[e] = (_Float16)v;
  }
  if (lane < 4)
    XW[lane] = *(const float4*)(inputs + ((b * NN + n_base + w * 4 + lane) * NT + t) * ND);

  // ---------- V fragments in registers (receiver-independent) ----------
  // vr[st][f].f[j] = (f16)(w1s[f*32+q*8+j] . x[st*16+r])  -- element-
  // identical arithmetic to the old staged Vh (same dot order, RNE cvt).
  Frag8 vr[4][2];
  {
    float4 w1sv[16];                             // dies after this block
#pragma unroll
    for (int f = 0; f < 2; ++f)
#pragma unroll
      for (int j = 0; j < 8; ++j)
        w1sv[f * 8 + j] = *(const float4*)(fc1_w + 516 + (f * 32 + q * 8 + j) * 8);
#pragma unroll
    for (int st = 0; st < 4; ++st) {
      const float4 xs = *(const float4*)(inputs + ((b * NN + st * 16 + r) * NT + t) * ND);
#pragma unroll
      for (int f = 0; f < 2; ++f)
#pragma unroll
        for (int j = 0; j < 8; ++j) {
          const float4 ww = w1sv[f * 8 + j];
          vr[st][f].f[j] = (_Float16)(ww.x*xs.x + ww.y*xs.y + ww.z*xs.z + ww.w*xs.w);
        }
    }
  }

  // ---------- W2 (relation 1) f16 B-frags, register-resident ----------
  Frag8 bfr[4][2];
  float b2l[4];
#pragma unroll
  for (int nt = 0; nt < 4; ++nt) {
    const int o = nt * 16 + r;
    b2l[nt] = fc2_b[64 + o];
#pragma unroll
    for (int ks = 0; ks < 2; ++ks) {
      const float* p = fc2_w + 4096 + o * 64 + ks * 32 + q * 8;
      const float4 c0 = *(const float4*)p;
      const float4 c1 = *(const float4*)(p + 4);
      bfr[nt][ks].u[0] = pk16(c0.x, c0.y);
      bfr[nt][ks].u[1] = pk16(c0.z, c0.w);
      bfr[nt][ks].u[2] = pk16(c1.x, c1.y);
      bfr[nt][ks].u[3] = pk16(c1.z, c1.w);
    }
  }

  // ---------- node weights hoisted BEFORE edge phase (r18 fix) ----------
  Frag8 B1f[4][2], B2f[4][2], B3f[2];
  float b1v[4], b2v[4];
  float4 w1xv[4];
#pragma unroll
  for (int nt = 0; nt < 4; ++nt) {
    const int o = nt * 16 + r;
    b1v[nt]  = out1_b[o];
    b2v[nt]  = out2_b[o];
    w1xv[nt] = *(const float4*)(out1_w + o * 68);
#pragma unroll
    for (int ks = 0; ks < 2; ++ks) {
      const float* p1 = out1_w + o * 68 + 4 + ks * 32 + q * 8;
      const float4 c0 = *(const float4*)p1;
      const float4 c1 = *(const float4*)(p1 + 4);
      B1f[nt][ks].u[0] = pk16(c0.x, c0.y); B1f[nt][ks].u[1] = pk16(c0.z, c0.w);
      B1f[nt][ks].u[2] = pk16(c1.x, c1.y); B1f[nt][ks].u[3] = pk16(c1.z, c1.w);
      const float* p2 = out2_w + o * 64 + ks * 32 + q * 8;
      const float4 e0 = *(const float4*)p2;
      const float4 e1 = *(const float4*)(p2 + 4);
      B2f[nt][ks].u[0] = pk16(e0.x, e0.y); B2f[nt][ks].u[1] = pk16(e0.z, e0.w);
      B2f[nt][ks].u[2] = pk16(e1.x, e1.y); B2f[nt][ks].u[3] = pk16(e1.z, e1.w);
    }
  }
#pragma unroll
  for (int ks = 0; ks < 2; ++ks) {
    const float* p3 = out3_w + (r & 3) * 64 + ks * 32 + q * 8;
    const float4 c0 = *(const float4*)p3;
    const float4 c1 = *(const float4*)(p3 + 4);
    B3f[ks].u[0] = pk16(c0.x, c0.y); B3f[ks].u[1] = pk16(c0.z, c0.w);
    B3f[ks].u[2] = pk16(c1.x, c1.y); B3f[ks].u[3] = pk16(c1.z, c1.w);
  }
  const float b3o = out3_b[r & 3];

  lds_fence();   // staging writes ordered before edge-phase LDS reads

  // ---------- edge phase: 4 receivers, wave-private, no barriers ----------
#pragma unroll 1
  for (int np = 0; np < 4; ++np) {
    Frag8 pa0, pa1;
    pa0.f = *(const f16x8*)(PhW + np * 64 + q * 8);        // k = q*8..
    pa1.f = *(const f16x8*)(PhW + np * 64 + 32 + q * 8);   // k = 32+q*8..

    float ag[4] = {0.f, 0.f, 0.f, 0.f};
#pragma unroll
    for (int st = 0; st < 4; ++st) {
      // rt: senders st*16 + q*4 + {0..3}; broadcast across r
      const f16x4 rt4 = *(const f16x4*)(RlW + np * 64 + st * 16 + q * 4);

      // h = relu(P + V), packed f16 (V from registers)
      Frag8 a0, a1;
      const f16x2 z = {(_Float16)0.f, (_Float16)0.f};
#pragma unroll
      for (int j = 0; j < 4; ++j) {
        a0.h[j] = __builtin_elementwise_max((f16x2)(pa0.h[j] + vr[st][0].h[j]), z);
        a1.h[j] = __builtin_elementwise_max((f16x2)(pa1.h[j] + vr[st][1].h[j]), z);
      }

      __builtin_amdgcn_s_setprio(1);
      const f32x4 z4 = {0.f, 0.f, 0.f, 0.f};
#pragma unroll
      for (int nt = 0; nt < 4; ++nt) {
        f32x4 d = {b2l[nt], b2l[nt], b2l[nt], b2l[nt]};
        d = MFMA16(a0.f, bfr[nt][0].f, d);
        d = MFMA16(a1.f, bfr[nt][1].f, d);
        const f32x4 p = __builtin_elementwise_max(d, z4);
        float s = ag[nt];
        s += (float)rt4[0] * p[0];
        s += (float)rt4[1] * p[1];
        s += (float)rt4[2] * p[2];
        s += (float)rt4[3] * p[3];
        ag[nt] = s;
      }
      __builtin_amdgcn_s_setprio(0);
    }

    // reduce over q (disjoint 16-sender partials)
#pragma unroll
    for (int nt = 0; nt < 4; ++nt) {
      float s = ag[nt];
      s += __shfl_xor(s, 16); s += __shfl_xor(s, 32);
      ag[nt] = s;
    }
    const float aval = (q == 0) ? ag[0] : (q == 1) ? ag[1] : (q == 2) ? ag[2] : ag[3];
    Reg[np * 72 + lane] = (_Float16)aval;        // agg row np; o = lane
  }

  lds_fence();   // agg writes ordered before node reads

  // ---------- node phase: wave-private rows, weights pre-loaded ----------
  // (r18-verified path: A row i holds agg row i&3; C/D row q*4+reg, col r;
  //  valid results from q==0 replicas.)
  // Layer 1: h1[n][o] = relu(b1 + x[n]·w1x + agg[n]·W1a[o])
  {
    Frag8 A0, A1;
    A0.f = *(const f16x8*)(Reg + (r & 3) * 72 + q * 8);
    A1.f = *(const f16x8*)(Reg + (r & 3) * 72 + 32 + q * 8);
    f32x4 d0 = {b1v[0], b1v[0], b1v[0], b1v[0]};
    f32x4 d1 = {b1v[1], b1v[1], b1v[1], b1v[1]};
    f32x4 d2 = {b1v[2], b1v[2], b1v[2], b1v[2]};
    f32x4 d3 = {b1v[3], b1v[3], b1v[3], b1v[3]};
    d0 = MFMA16(A0.f, B1f[0][0].f, d0); d0 = MFMA16(A1.f, B1f[0][1].f, d0);
    d1 = MFMA16(A0.f, B1f[1][0].f, d1); d1 = MFMA16(A1.f, B1f[1][1].f, d1);
    d2 = MFMA16(A0.f, B1f[2][0].f, d2); d2 = MFMA16(A1.f, B1f[2][1].f, d2);
    d3 = MFMA16(A0.f, B1f[3][0].f, d3); d3 = MFMA16(A1.f, B1f[3][1].f, d3);
    if (q == 0) {
#pragma unroll
      for (int reg = 0; reg < 4; ++reg) {
        const float4 x = XW[reg];
        const float xv0 = x.x*w1xv[0].x + x.y*w1xv[0].y + x.z*w1xv[0].z + x.w*w1xv[0].w;
        const float xv1 = x.x*w1xv[1].x + x.y*w1xv[1].y + x.z*w1xv[1].z + x.w*w1xv[1].w;
        const float xv2 = x.x*w1xv[2].x + x.y*w1xv[2].y + x.z*w1xv[2].z + x.w*w1xv[2].w;
        const float xv3 = x.x*w1xv[3].x + x.y*w1xv[3].y + x.z*w1xv[3].z + x.w*w1xv[3].w;
        Reg[reg * 72 +  0 + r] = (_Float16)fmaxf(d0[reg] + xv0, 0.f);
        Reg[reg * 72 + 16 + r] = (_Float16)fmaxf(d1[reg] + xv1, 0.f);
        Reg[reg * 72 + 32 + r] = (_Float16)fmaxf(d2[reg] + xv2, 0.f);
        Reg[reg * 72 + 48 + r] = (_Float16)fmaxf(d3[reg] + xv3, 0.f);
      }
    }
  }
  lds_fence();   // h1 ordered before layer-2 reads

  // Layer 2: h2 = relu(b2 + h1·W2o^T)
  {
    Frag8 A0, A1;
    A0.f = *(const f16x8*)(Reg + (r & 3) * 72 + q * 8);
    A1.f = *(const f16x8*)(Reg + (r & 3) * 72 + 32 + q * 8);
    f32x4 d0 = {b2v[0], b2v[0], b2v[0], b2v[0]};
    f32x4 d1 = {b2v[1], b2v[1], b2v[1], b2v[1]};
    f32x4 d2 = {b2v[2], b2v[2], b2v[2], b2v[2]};
    f32x4 d3 = {b2v[3], b2v[3], b2v[3], b2v[3]};
    d0 = MFMA16(A0.f, B2f[0][0].f, d0); d0 = MFMA16(A1.f, B2f[0][1].f, d0);
    d1 = MFMA16(A0.f, B2f[1][0].f, d1); d1 = MFMA16(A1.f, B2f[1][1].f, d1);
    d2 = MFMA16(A0.f, B2f[2][0].f, d2); d2 = MFMA16(A1.f, B2f[2][1].f, d2);
    d3 = MFMA16(A0.f, B2f[3][0].f, d3); d3 = MFMA16(A1.f, B2f[3][1].f, d3);
    if (q == 0) {
#pragma unroll
      for (int reg = 0; reg < 4; ++reg) {
        Reg[reg * 72 +  0 + r] = (_Float16)fmaxf(d0[reg], 0.f);
        Reg[reg * 72 + 16 + r] = (_Float16)fmaxf(d1[reg], 0.f);
        Reg[reg * 72 + 32 + r] = (_Float16)fmaxf(d2[reg], 0.f);
        Reg[reg * 72 + 48 + r] = (_Float16)fmaxf(d3[reg], 0.f);
      }
    }
  }
  lds_fence();   // h2 ordered before layer-3 reads

  // Layer 3: delta[n][dm] = b3[dm] + h2[n]·W3[dm]; out = x + delta
  {
    Frag8 A0, A1;
    A0.f = *(const f16x8*)(Reg + (r & 3) * 72 + q * 8);
    A1.f = *(const f16x8*)(Reg + (r & 3) * 72 + 32 + q * 8);
    f32x4 d = {b3o, b3o, b3o, b3o};
    d = MFMA16(A0.f, B3f[0].f, d);
    d = MFMA16(A1.f, B3f[1].f, d);
    if (q == 0 && r < 4) {   // rows 0-3 = reg, cols 0-3 = dm = r
      const float* xw = (const float*)XW;
#pragma unroll
      for (int reg = 0; reg < 4; ++reg) {
        const int n = w * 4 + reg;
        out[((b * NN + n_base + n) * NTO + t) * ND + r] = xw[reg * 4 + r] + d[reg];
      }
    }
  }
}

extern "C" void kernel_launch(void* const* d_in, const int* in_sizes, int n_in,
                              void* d_out, int out_size, void* d_ws, size_t ws_size,
                              hipStream_t stream) {
  const float* inputs   = (const float*)d_in[0];
  const float* rel_type = (const float*)d_in[1];
  const float* fc1_w  = (const float*)d_in[4];
  const float* fc1_b  = (const float*)d_in[5];
  const float* fc2_w  = (const float*)d_in[6];
  const float* fc2_b  = (const float*)d_in[7];
  const float* out1_w = (const float*)d_in[8];
  const float* out1_b = (const float*)d_in[9];
  const float* out2_w = (const float*)d_in[10];
  const float* out2_b = (const float*)d_in[11];
  const float* out3_w = (const float*)d_in[12];
  const float* out3_b = (const float*)d_in[13];
  float* out = (float*)d_out;

  nri_fused_kernel<<<NB * NTO * 4, 256, 0, stream>>>(
      inputs, rel_type, fc1_w, fc1_b, fc2_w, fc2_b,
      out1_w, out1_b, out2_w, out2_b, out3_w, out3_b, out);
}

// Round 14
// 111.678 us; speedup vs baseline: 1.3879x; 1.3879x over previous
//
#include <hip/hip_runtime.h>

// NRI MLP decoder, round 20: merge of the two best verified variants.
// r12: V-frags REGISTER-RESIDENT across the edge phase (8 frags loaded
// once; removes 24/32 edge ds_read_b128, per-receiver cold LDS chains,
// and the prefetch dbuf) -- measured sub-cutoff (<39.4us), conflicts
// predicted ~250k. r16: T5 s_setprio around the MFMA/epilogue cluster
// (edge phase is barrier-free -> wave role diversity) -- measured tied-
// best bench 112.0. Both verified absmax 0.03125; both keep VGPR in the
// proven-equal 65-128 tier. r19 falsified the convoy theory (0 barriers
// = 2x slower via VGPR-156 occupancy drop + 4x per-wave redundancy) and
// confirmed resident waves scale with VGPR only above ~128 -- so this
// combo's ~110 VGPR is safe. Final ledger: all other levers falsified;
// if this is flat, 38.5-40us kernel is the structural floor for this
// decomposition.
// B=8, N=64, T=50 (49 used), D=4, H=64, K=2 (only relation i=1), E=4032.
// Grid = B*49*4 = 1568 blocks, 256 threads (4 waves); block = (b,t,16
// receivers); wave = 4 receivers serial. Edge fc2 GEMM + 3 node layers on
// mfma_f32_16x16x32_f16; fp32 accumulate everywhere.

#define NB 8
#define NN 64
#define NT 50
#define NTO 49
#define ND 4
#define NE 4032

typedef _Float16 f16x8 __attribute__((ext_vector_type(8)));
typedef _Float16 f16x4 __attribute__((ext_vector_type(4)));
typedef _Float16 f16x2 __attribute__((ext_vector_type(2)));
typedef float f32x4 __attribute__((ext_vector_type(4)));
typedef float f32x2 __attribute__((ext_vector_type(2)));

union Frag8 { unsigned u[4]; f16x8 f; f16x2 h[4]; };

__device__ __forceinline__ unsigned pk16(float lo, float hi) {
  return __builtin_bit_cast(unsigned, __builtin_amdgcn_cvt_pkrtz(lo, hi));
}

#define MFMA16(A, B, C) __builtin_amdgcn_mfma_f32_16x16x32_f16((A), (B), (C), 0, 0, 0)

__global__ __launch_bounds__(256) void nri_fused_kernel(
    const float* __restrict__ inputs,   // (B,N,T,D)
    const float* __restrict__ rel_type, // (B,1,E,2)
    const float* __restrict__ fc1_w,    // (2,64,8)
    const float* __restrict__ fc1_b,    // (2,64)
    const float* __restrict__ fc2_w,    // (2,64,64)
    const float* __restrict__ fc2_b,    // (2,64)
    const float* __restrict__ out1_w,   // (64,68)
    const float* __restrict__ out1_b,   // (64)
    const float* __restrict__ out2_w,   // (64,64)
    const float* __restrict__ out2_b,   // (64)
    const float* __restrict__ out3_w,   // (4,64)
    const float* __restrict__ out3_b,   // (4)
    float* __restrict__ out)            // (B,N,49,4)
{
  // Manual LDS layout, 15872 B total (all sub-arrays 16B-aligned):
  //   [    0,  9216) Vh   f16[64*72]  V[s][k]          (edge only)
  //   [    0,  2304) H1L  f16[16*72]  alias, post-edge
  //   [ 4608,  6912) H2L  f16[16*72]  alias, post-edge
  //   [ 9216, 11264) Ph   f16[16*64]  U[n][k]+b1[k]
  //   [11264, 13312) Rl   f16[16*64]  rt[n][s]
  //   [13312, 13568) Xl   float4[16]
  //   [13568, 15872) AggL f16[16*72]
  __shared__ __align__(16) char smem[15872];
  _Float16* const Vh   = (_Float16*)(smem);
  _Float16* const H1L  = (_Float16*)(smem);
  _Float16* const H2L  = (_Float16*)(smem + 4608);
  _Float16* const Ph   = (_Float16*)(smem + 9216);
  _Float16* const Rl   = (_Float16*)(smem + 11264);
  float4*   const Xl   = (float4*)  (smem + 13312);
  _Float16* const AggL = (_Float16*)(smem + 13568);

  const int bid    = blockIdx.x;
  const int tile   = bid & 3;
  const int t      = (bid >> 2) % NTO;
  const int b      = bid / (4 * NTO);
  const int n_base = tile * 16;
  const int tid  = threadIdx.x;
  const int lane = tid & 63;
  const int w    = tid >> 6;
  const int q    = lane >> 4;
  const int r    = lane & 15;

  // ---------------- staging ----------------
  {
    const int k = lane;
    const float4 w1r = *(const float4*)(fc1_w + 512 + k * 8);
    const float4 w1s = *(const float4*)(fc1_w + 516 + k * 8);
    const float  b1k = fc1_b[64 + k];
#pragma unroll
    for (int ii = 0; ii < 16; ++ii) {            // V rows i = w, w+4, ...
      const int i = ii * 4 + w;
      const float4 x = *(const float4*)(inputs + ((b * NN + i) * NT + t) * ND);
      Vh[i * 72 + k] = (_Float16)(w1s.x*x.x + w1s.y*x.y + w1s.z*x.z + w1s.w*x.w);
    }
#pragma unroll
    for (int ii = 0; ii < 4; ++ii) {             // P rows (stride 64)
      const int i = ii * 4 + w;
      const float4 x = *(const float4*)(inputs + ((b * NN + n_base + i) * NT + t) * ND);
      Ph[i * 64 + k] = (_Float16)(b1k + w1r.x*x.x + w1r.y*x.y + w1r.z*x.z + w1r.w*x.w);
    }
  }
#pragma unroll
  for (int ii = 0; ii < 4; ++ii) {               // rt: 1024 entries, f16
    const int idx = ii * 256 + tid;
    const int i = idx >> 6, s = idx & 63;
    const int n = n_base + i;
    const float v = (s == n) ? 0.f
                  : rel_type[(b * NE + n * 63 + (s < n ? s : s - 1)) * 2 + 1];
    Rl[idx] = (_Float16)v;
  }
  if (tid < 16)
    Xl[tid] = *(const float4*)(inputs + ((b * NN + n_base + tid) * NT + t) * ND);

  // ---- W2 (relation 1) f16 B-frags, register-resident
  Frag8 bfr[4][2];
  float b2l[4];
#pragma unroll
  for (int nt = 0; nt < 4; ++nt) {
    const int o = nt * 16 + r;
    b2l[nt] = fc2_b[64 + o];
#pragma unroll
    for (int ks = 0; ks < 2; ++ks) {
      const float* p = fc2_w + 4096 + o * 64 + ks * 32 + q * 8;
      const float4 c0 = *(const float4*)p;
      const float4 c1 = *(const float4*)(p + 4);
      bfr[nt][ks].u[0] = pk16(c0.x, c0.y);
      bfr[nt][ks].u[1] = pk16(c0.z, c0.w);
      bfr[nt][ks].u[2] = pk16(c1.x, c1.y);
      bfr[nt][ks].u[3] = pk16(c1.z, c1.w);
    }
  }
  __syncthreads();

  // ---------------- edge phase: wave w, 4 serial receivers ----------------
  // V frags depend only on (st,r,q): load ALL 8 once (32 VGPR), reuse
  // across the 4 receivers (r12). No per-receiver LDS chain, no dbuf.
  Frag8 vr[4][2];
#pragma unroll
  for (int st = 0; st < 4; ++st) {
    const _Float16* vp = Vh + (st * 16 + r) * 72 + q * 8;
    vr[st][0].f = *(const f16x8*)vp;
    vr[st][1].f = *(const f16x8*)(vp + 32);
  }

#pragma unroll 1
  for (int np = 0; np < 4; ++np) {
    const int ni = w * 4 + np;
    Frag8 pa0, pa1;
    pa0.f = *(const f16x8*)(Ph + ni * 64 + q * 8);        // k = q*8..
    pa1.f = *(const f16x8*)(Ph + ni * 64 + 32 + q * 8);   // k = 32+q*8..

    float ag[4] = {0.f, 0.f, 0.f, 0.f};
#pragma unroll
    for (int st = 0; st < 4; ++st) {
      // rt for this st: senders st*16 + q*4 + {0..3}; broadcast across r
      // (16 lanes same address) -> conflict-free 8B ds_read.
      const f16x4 rt4 = *(const f16x4*)(Rl + ni * 64 + st * 16 + q * 4);

      // h = relu(P + V), packed f16 (V from registers)
      Frag8 a0, a1;
      const f16x2 z = {(_Float16)0.f, (_Float16)0.f};
#pragma unroll
      for (int j = 0; j < 4; ++j) {
        a0.h[j] = __builtin_elementwise_max((f16x2)(pa0.h[j] + vr[st][0].h[j]), z);
        a1.h[j] = __builtin_elementwise_max((f16x2)(pa1.h[j] + vr[st][1].h[j]), z);
      }

      // T5 (r16): favor this wave while it drains the MFMA+epilogue
      // cluster; co-resident waves in staging/reduce phases yield slots.
      __builtin_amdgcn_s_setprio(1);
      const f32x4 z4 = {0.f, 0.f, 0.f, 0.f};
#pragma unroll
      for (int nt = 0; nt < 4; ++nt) {
        f32x4 d = {b2l[nt], b2l[nt], b2l[nt], b2l[nt]};
        d = MFMA16(a0.f, bfr[nt][0].f, d);
        d = MFMA16(a1.f, bfr[nt][1].f, d);
        // p = relu(m) in f32 (packed max); ag += f16(rt)*f32(p) -> fma_mix
        const f32x4 p = __builtin_elementwise_max(d, z4);
        float s = ag[nt];
        s += (float)rt4[0] * p[0];
        s += (float)rt4[1] * p[1];
        s += (float)rt4[2] * p[2];
        s += (float)rt4[3] * p[3];
        ag[nt] = s;
      }
      __builtin_amdgcn_s_setprio(0);
    }

    // reduce over q (each q-group holds a disjoint 16-sender partial)
#pragma unroll
    for (int nt = 0; nt < 4; ++nt) {
      float s = ag[nt];
      s += __shfl_xor(s, 16); s += __shfl_xor(s, 32);
      ag[nt] = s;
    }
    const float aval = (q == 0) ? ag[0] : (q == 1) ? ag[1] : (q == 2) ? ag[2] : ag[3];
    AggL[ni * 72 + lane] = (_Float16)aval;   // o = lane
  }

  // ---- node weights (independent of agg; overlap barrier drain)
  const int o = w * 16 + r;
  Frag8 B1[2], B2[2];
#pragma unroll
  for (int ks = 0; ks < 2; ++ks) {
    const float* p1 = out1_w + o * 68 + 4 + ks * 32 + q * 8;
    const float4 c0 = *(const float4*)p1;
    const float4 c1 = *(const float4*)(p1 + 4);
    B1[ks].u[0] = pk16(c0.x, c0.y); B1[ks].u[1] = pk16(c0.z, c0.w);
    B1[ks].u[2] = pk16(c1.x, c1.y); B1[ks].u[3] = pk16(c1.z, c1.w);
    const float* p2 = out2_w + o * 64 + ks * 32 + q * 8;
    const float4 e0 = *(const float4*)p2;
    const float4 e1 = *(const float4*)(p2 + 4);
    B2[ks].u[0] = pk16(e0.x, e0.y); B2[ks].u[1] = pk16(e0.z, e0.w);
    B2[ks].u[2] = pk16(e1.x, e1.y); B2[ks].u[3] = pk16(e1.z, e1.w);
  }
  const float4 w1x = *(const float4*)(out1_w + o * 68);
  const float b1o = out1_b[o];
  const float b2o = out2_b[o];
  __syncthreads();   // AggL complete; Vh dead from here (H1L/H2L alias it)

  // ---------------- node phase (16 rows) ----------------
  // Layer 1: h1[n][o] = relu(b1 + x[n]·w1x + agg[n]·W1k[o])
  {
    Frag8 A0, A1;
    A0.f = *(const f16x8*)(AggL + r * 72 + q * 8);
    A1.f = *(const f16x8*)(AggL + r * 72 + 32 + q * 8);
    f32x4 d = {b1o, b1o, b1o, b1o};
    d = MFMA16(A0.f, B1[0].f, d);
    d = MFMA16(A1.f, B1[1].f, d);
#pragma unroll
    for (int reg = 0; reg < 4; ++reg) {
      const int n = q * 4 + reg;
      const float4 x = Xl[n];
      const float hv = d[reg] + x.x*w1x.x + x.y*w1x.y + x.z*w1x.z + x.w*w1x.w;
      H1L[n * 72 + o] = (_Float16)fmaxf(hv, 0.f);
    }
  }
  __syncthreads();

  // Layer 2: h2 = relu(b2 + h1·W2o^T)
  {
    Frag8 A0, A1;
    A0.f = *(const f16x8*)(H1L + r * 72 + q * 8);
    A1.f = *(const f16x8*)(H1L + r * 72 + 32 + q * 8);
    f32x4 d = {b2o, b2o, b2o, b2o};
    d = MFMA16(A0.f, B2[0].f, d);
    d = MFMA16(A1.f, B2[1].f, d);
#pragma unroll
    for (int reg = 0; reg < 4; ++reg) {
      const int n = q * 4 + reg;
      H2L[n * 72 + o] = (_Float16)fmaxf(d[reg], 0.f);
    }
  }
  __syncthreads();

  // Layer 3 (wave 0): delta[n][dm] = b3[dm] + h2[n]·W3[dm]; out = x + delta
  if (w == 0) {
    Frag8 B3[2];
#pragma unroll
    for (int ks = 0; ks < 2; ++ks) {
      const float* p3 = out3_w + (r & 3) * 64 + ks * 32 + q * 8;
      const float4 c0 = *(const float4*)p3;
      const float4 c1 = *(const float4*)(p3 + 4);
      B3[ks].u[0] = pk16(c0.x, c0.y); B3[ks].u[1] = pk16(c0.z, c0.w);
      B3[ks].u[2] = pk16(c1.x, c1.y); B3[ks].u[3] = pk16(c1.z, c1.w);
    }
    Frag8 A0, A1;
    A0.f = *(const f16x8*)(H2L + r * 72 + q * 8);
    A1.f = *(const f16x8*)(H2L + r * 72 + 32 + q * 8);
    const float b3o = out3_b[r & 3];
    f32x4 d = {b3o, b3o, b3o, b3o};
    d = MFMA16(A0.f, B3[0].f, d);
    d = MFMA16(A1.f, B3[1].f, d);
    if (r < 4) {  // valid cols; rows q*4+reg all valid
      const float* xf = (const float*)Xl;
#pragma unroll
      for (int reg = 0; reg < 4; ++reg) {
        const int n = q * 4 + reg;
        out[((b * NN + n_base + n) * NTO + t) * ND + r] = xf[n * 4 + r] + d[reg];
      }
    }
  }
}

extern "C" void kernel_launch(void* const* d_in, const int* in_sizes, int n_in,
                              void* d_out, int out_size, void* d_ws, size_t ws_size,
                              hipStream_t stream) {
  const float* inputs   = (const float*)d_in[0];
  const float* rel_type = (const float*)d_in[1];
  const float* fc1_w  = (const float*)d_in[4];
  const float* fc1_b  = (const float*)d_in[5];
  const float* fc2_w  = (const float*)d_in[6];
  const float* fc2_b  = (const float*)d_in[7];
  const float* out1_w = (const float*)d_in[8];
  const float* out1_b = (const float*)d_in[9];
  const float* out2_w = (const float*)d_in[10];
  const float* out2_b = (const float*)d_in[11];
  const float* out3_w = (const float*)d_in[12];
  const float* out3_b = (const float*)d_in[13];
  float* out = (float*)d_out;

  nri_fused_kernel<<<NB * NTO * 4, 256, 0, stream>>>(
      inputs, rel_type, fc1_w, fc1_b, fc2_w, fc2_b,
      out1_w, out1_b, out2_w, out2_b, out3_w, out3_b, out);
}